// Round 1
// baseline (14.231 us; speedup 1.0000x reference)
//
#include <hip/hip_runtime.h>

// KANRNNEncoder: the T=1024 scan has dependency horizon 2 (only h[:, :24]
// feeds the recurrence, and those columns are pure functions of x at the
// previous step). Entire scan collapses to a closed form over x[:, T-2:T, :].

constexpr int Bc = 1024, Tc = 1024, Fc = 8, Hc = 256, Kc = 8, Lc = 64;

__device__ __forceinline__ float sigm(float v) {
    return 1.0f / (1.0f + __expf(-v));
}

__global__ __launch_bounds__(256) void kan_rnn_collapsed(
    const float* __restrict__ x,     // (B,T,F)
    const float* __restrict__ a_in,  // (F,K) flat 64
    const float* __restrict__ b_in,  // (F,K)
    const float* __restrict__ a_h,   // (H,K) flat 2048
    const float* __restrict__ b_h,   // (H,K)
    const float* __restrict__ W,     // (L,H)
    const float* __restrict__ bl,    // (L,)
    float* __restrict__ out)         // (B,L)
{
    __shared__ float hT[4][Hc];      // one 256-float hT vector per wave
    const int t = threadIdx.x;
    const int w = t >> 6;            // wave id within block
    const int l = t & 63;            // lane
    const int b = blockIdx.x * 4 + w;

    const float* xb = x + (size_t)b * Tc * Fc;
    // Only two timesteps matter.
    const float x1  = xb[(Tc - 1) * Fc + (l >> 3)];  // x[b, T-1, l/8]
    const float x20 = xb[(Tc - 2) * Fc + 0];
    const float x21 = xb[(Tc - 2) * Fc + 1];
    const float x22 = xb[(Tc - 2) * Fc + 2];
    const float x2v[3] = {x20, x21, x22};

    // hT[c] for c = l (input-basis path, uses x at T-1)
    hT[w][l] = sigm(2.0f * sigm(a_in[l] * (x1 - b_in[l])));

    // hT[64 + j] for j = l, l+64, l+128 (hidden-basis path, uses x at T-2)
    const int hp0 = l >> 3;          // l/8 in 0..7
    #pragma unroll
    for (int m = 0; m < 3; ++m) {
        const int hp = hp0 + 8 * m;  // h' in 0..23
        const int j  = l + 64 * m;   // j  in 0..191
        // s = h_{T-1}[b, h'] = sigmoid(input basis at T-2, column h')
        const float s  = sigm(2.0f * sigm(a_in[hp] * (x2v[m] - b_in[hp])));
        hT[w][64 + j]  = sigm(2.0f * sigm(a_h[j] * (s - b_h[j])));
    }
    __syncthreads();

    // z[b, l] = b_lat[l] + dot(hT, W_lat[l, :])
    float acc = bl[l];
    const float4* Wrow = reinterpret_cast<const float4*>(W + (size_t)l * Hc);
    const float4* hrow = reinterpret_cast<const float4*>(hT[w]);
    #pragma unroll 8
    for (int q = 0; q < Hc / 4; ++q) {
        const float4 wv = Wrow[q];
        const float4 hv = hrow[q];   // same addr across lanes -> LDS broadcast
        acc += wv.x * hv.x + wv.y * hv.y + wv.z * hv.z + wv.w * hv.w;
    }
    out[(size_t)b * Lc + l] = acc;
}

extern "C" void kernel_launch(void* const* d_in, const int* in_sizes, int n_in,
                              void* d_out, int out_size, void* d_ws, size_t ws_size,
                              hipStream_t stream) {
    const float* x    = (const float*)d_in[0];
    const float* a_in = (const float*)d_in[1];
    const float* b_in = (const float*)d_in[2];
    const float* a_h  = (const float*)d_in[3];
    const float* b_h  = (const float*)d_in[4];
    const float* W    = (const float*)d_in[5];
    const float* bl   = (const float*)d_in[6];
    float* out = (float*)d_out;

    dim3 grid(Bc / 4), block(256);
    kan_rnn_collapsed<<<grid, block, 0, stream>>>(x, a_in, b_in, a_h, b_h, W, bl, out);
}

// Round 2
// 10.364 us; speedup vs baseline: 1.3730x; 1.3730x over previous
//
#include <hip/hip_runtime.h>

// KANRNNEncoder: the T=1024 scan has dependency horizon 2 (only h[:, :24]
// feeds the recurrence, and those columns are pure functions of x at the
// previous step). Entire scan collapses to a closed form over x[:, T-2:T, :].
//
// R1: stage W_lat (64KB) in LDS via coalesced loads — the R0 version read W
// row-per-lane from global (64 distinct cache lines per load instr). Rotate
// the dot-product chunk index by lane so the stride-1KB LDS reads spread
// across all bank groups. 4 partial accumulators break the FMA chain.

constexpr int Bc = 1024, Tc = 1024, Fc = 8, Hc = 256, Kc = 8, Lc = 64;

__device__ __forceinline__ float sigm(float v) {
    return 1.0f / (1.0f + __expf(-v));
}

__global__ __launch_bounds__(256) void kan_rnn_collapsed(
    const float* __restrict__ x,     // (B,T,F)
    const float* __restrict__ a_in,  // (F,K) flat 64
    const float* __restrict__ b_in,  // (F,K)
    const float* __restrict__ a_h,   // (H,K) flat 2048
    const float* __restrict__ b_h,   // (H,K)
    const float* __restrict__ W,     // (L,H) 64x256
    const float* __restrict__ bl,    // (L,)
    float* __restrict__ out)         // (B,L)
{
    __shared__ float Ws[Lc * Hc];    // 64 KB, linear row-major
    __shared__ float hT[4][Hc];      // one 256-float hT vector per wave
    const int t = threadIdx.x;
    const int w = t >> 6;            // wave id within block
    const int l = t & 63;            // lane
    const int b = blockIdx.x * 4 + w;

    // ---- stage W into LDS, coalesced float4 ----
    {
        const float4* Wg = reinterpret_cast<const float4*>(W);
        float4* Wl = reinterpret_cast<float4*>(Ws);
        #pragma unroll
        for (int k = 0; k < (Lc * Hc / 4) / 256; ++k)   // 16 iters
            Wl[t + 256 * k] = Wg[t + 256 * k];
    }

    // ---- closed-form hT ----
    const float* xb = x + (size_t)b * Tc * Fc;
    const float x1  = xb[(Tc - 1) * Fc + (l >> 3)];  // x[b, T-1, l/8]
    const float x20 = xb[(Tc - 2) * Fc + 0];
    const float x21 = xb[(Tc - 2) * Fc + 1];
    const float x22 = xb[(Tc - 2) * Fc + 2];
    const float x2v[3] = {x20, x21, x22};

    hT[w][l] = sigm(2.0f * sigm(a_in[l] * (x1 - b_in[l])));

    const int hp0 = l >> 3;          // l/8 in 0..7
    #pragma unroll
    for (int m = 0; m < 3; ++m) {
        const int hp = hp0 + 8 * m;  // h' in 0..23
        const int j  = l + 64 * m;   // j  in 0..191
        const float s  = sigm(2.0f * sigm(a_in[hp] * (x2v[m] - b_in[hp])));
        hT[w][64 + j]  = sigm(2.0f * sigm(a_h[j] * (s - b_h[j])));
    }
    __syncthreads();

    // ---- z[b, l] = b_lat[l] + dot(hT, W_lat[l, :]) ----
    // Chunk index rotated by lane: lane l at step q reads chunk (q+l)&63 of
    // its own W row (LDS row stride 1KB would otherwise put all 64 lanes on
    // the same 4-bank group). hT reads rotate identically -> conflict-free.
    const float4* Wrow = reinterpret_cast<const float4*>(Ws) + l * (Hc / 4);
    const float4* hrow = reinterpret_cast<const float4*>(hT[w]);
    float a0 = 0.f, a1 = 0.f, a2 = 0.f, a3 = 0.f;
    #pragma unroll 8
    for (int q = 0; q < Hc / 4; q += 4) {
        const int q0 = (q + 0 + l) & 63, q1 = (q + 1 + l) & 63;
        const int q2 = (q + 2 + l) & 63, q3 = (q + 3 + l) & 63;
        float4 wv, hv;
        wv = Wrow[q0]; hv = hrow[q0];
        a0 += wv.x * hv.x + wv.y * hv.y + wv.z * hv.z + wv.w * hv.w;
        wv = Wrow[q1]; hv = hrow[q1];
        a1 += wv.x * hv.x + wv.y * hv.y + wv.z * hv.z + wv.w * hv.w;
        wv = Wrow[q2]; hv = hrow[q2];
        a2 += wv.x * hv.x + wv.y * hv.y + wv.z * hv.z + wv.w * hv.w;
        wv = Wrow[q3]; hv = hrow[q3];
        a3 += wv.x * hv.x + wv.y * hv.y + wv.z * hv.z + wv.w * hv.w;
    }
    out[(size_t)b * Lc + l] = bl[l] + ((a0 + a1) + (a2 + a3));
}

extern "C" void kernel_launch(void* const* d_in, const int* in_sizes, int n_in,
                              void* d_out, int out_size, void* d_ws, size_t ws_size,
                              hipStream_t stream) {
    const float* x    = (const float*)d_in[0];
    const float* a_in = (const float*)d_in[1];
    const float* b_in = (const float*)d_in[2];
    const float* a_h  = (const float*)d_in[3];
    const float* b_h  = (const float*)d_in[4];
    const float* W    = (const float*)d_in[5];
    const float* bl   = (const float*)d_in[6];
    float* out = (float*)d_out;

    dim3 grid(Bc / 4), block(256);
    kan_rnn_collapsed<<<grid, block, 0, stream>>>(x, a_in, b_in, a_h, b_h, W, bl, out);
}